// Round 14
// baseline (107.445 us; speedup 1.0000x reference)
//
#include <hip/hip_runtime.h>

typedef __attribute__((ext_vector_type(4))) float f32x4;
typedef __attribute__((ext_vector_type(4))) int   i32x4;
typedef __attribute__((ext_vector_type(8))) int   i32x8;

#define MARGIN 0.1f
#define SC1 0x7F7F7F7F            // E8M0 unit scale (2^0) for all 32-blocks
#define INV_SCALE (1.0f/2048.0f)  // undo x*32 and e*64 pre-scaling

// fp4 e2m1 quantizer (verified R10): grid {0,.5,1,1.5,2,3,4,6}, sign bit3
__device__ __forceinline__ unsigned int nib4(float a) {
    const float m = fabsf(a);
    unsigned int c = (unsigned)(m > 0.25f) + (m > 0.75f) + (m > 1.25f) +
                     (m > 1.75f) + (m > 2.5f) + (m > 3.5f) + (m > 5.0f);
    return c | ((__builtin_bit_cast(unsigned int, a) >> 28) & 8u);
}
__device__ __forceinline__ unsigned int pack8(const float4 f0, const float4 f1,
                                              float s) {
    return  nib4(f0.x * s)         | (nib4(f0.y * s) << 4)  |
           (nib4(f0.z * s) << 8)   | (nib4(f0.w * s) << 12) |
           (nib4(f1.x * s) << 16)  | (nib4(f1.y * s) << 20) |
           (nib4(f1.z * s) << 24)  | (nib4(f1.w * s) << 28);
}
__device__ __forceinline__ i32x8 pad8(const i32x4 v) {
    return (i32x8){v[0], v[1], v[2], v[3], 0, 0, 0, 0};
}

// Kernel 1: L2-normalize inputs -> fp4(x*32) A-frags (layout verified R10);
// neg[b] = exact f32 dot(x, emb[target[b]]).
__global__ __launch_bounds__(256) void prep_kernel(
    const float* __restrict__ inputs, const float* __restrict__ emb,
    const int* __restrict__ target, unsigned char* __restrict__ x_frag4,
    float* __restrict__ neg)
{
    const int t = threadIdx.x;
    const int b = blockIdx.x;
    const float2 v = *reinterpret_cast<const float2*>(inputs + (size_t)b * 512 + t * 2);
    const int tgt = target[b];
    const float2 e = *reinterpret_cast<const float2*>(emb + (size_t)tgt * 512 + t * 2);
    float ss = v.x * v.x + v.y * v.y;
    float de = v.x * e.x + v.y * e.y;
    #pragma unroll
    for (int off = 32; off; off >>= 1) {
        ss += __shfl_down(ss, off);
        de += __shfl_down(de, off);
    }
    __shared__ float s_ss[4], s_de[4];
    const int wid = t >> 6, lane = t & 63;
    if (lane == 0) { s_ss[wid] = ss; s_de[wid] = de; }
    __syncthreads();
    const float tss = s_ss[0] + s_ss[1] + s_ss[2] + s_ss[3];
    const float tde = s_de[0] + s_de[1] + s_de[2] + s_de[3];
    const float inv = 1.0f / fmaxf(sqrtf(tss), 1e-12f);
    const float sc = inv * 32.0f;
    const int addr = (b >> 4) * 4096 + (t >> 6) * 1024 +
                     ((((t >> 4) & 3) * 16 + (b & 15)) * 16) + (t & 15);
    x_frag4[addr] = (unsigned char)(nib4(v.x * sc) | (nib4(v.y * sc) << 4));
    if (t == 0) neg[b] = tde * inv;
}

// Kernel 2 (fused, all-M, exclusive tiles): block bx owns tiles bx*4..bx*4+3
// (64 emb rows each) -> emb f32 read EXACTLY ONCE chip-wide (262 MB floor).
// Per tile: stage phase (2-deep chunk-pipelined reg-load f32 -> nib4 -> 16 KB
// frag-major LDS; staging regs die before compute), barrier, compute phase
// (4 FULLY-UNROLLED m-passes: areg from L2-resident x_frag4, 64 MX-MFMAs
// 16x16x128 fp4, fused relu-margin epilogue), barrier. ~2 blocks/CU overlap
// anti-phased stage/compute across blocks (R10-proven pattern).
__global__ __launch_bounds__(256) void gemm_fused_kernel(
    const unsigned char* __restrict__ x_frag4, const float* __restrict__ emb,
    const float* __restrict__ neg, float* __restrict__ partials)
{
    __shared__ unsigned char btile[16384];        // one fp4 tile, frag-major
    const int t = threadIdx.x;
    const int wid = t >> 6, lane = t & 63;
    const int lrow = lane & 15, g = lane >> 4;
    const int nf_s = t >> 6;                      // staging row-group 0..3

    float sum = 0.0f;

#define LOADC(dst, kk)                                                        \
    {                                                                         \
        _Pragma("unroll")                                                     \
        for (int i = 0; i < 8; ++i) dst[i] = sp[(kk) * 32 + i];               \
    }
#define WRITEC(src, kk)                                                       \
    {                                                                         \
        uint4 w;                                                              \
        w.x = pack8(src[0], src[1], 64.0f);                                   \
        w.y = pack8(src[2], src[3], 64.0f);                                   \
        w.z = pack8(src[4], src[5], 64.0f);                                   \
        w.w = pack8(src[6], src[7], 64.0f);                                   \
        *reinterpret_cast<uint4*>(btile + (kk) * 4096 + nf_s * 1024 +         \
                                  lane * 16) = w;                             \
    }

    #pragma unroll 1
    for (int j = 0; j < 4; ++j) {
        const int T = blockIdx.x * 4 + j;

        // ---- stage phase: f32 -> fp4 -> LDS (2-deep chunk pipeline) ----
        {
            const float4* sp = reinterpret_cast<const float4*>(
                emb + (size_t)(T * 64 + nf_s * 16 + lrow) * 512 + g * 32);
            float4 r0[8], r1[8];
            LOADC(r0, 0); LOADC(r1, 1);
            WRITEC(r0, 0); LOADC(r0, 2);
            WRITEC(r1, 1); LOADC(r1, 3);
            WRITEC(r0, 2);
            WRITEC(r1, 3);
        }
        __syncthreads();

        // ---- compute phase: 4 m-passes, fully unrolled ----
        const unsigned char* bb = btile + lane * 16;
        #pragma unroll
        for (int p = 0; p < 4; ++p) {
            i32x4 a[4][4];
            #pragma unroll
            for (int mf = 0; mf < 4; ++mf)
                #pragma unroll
                for (int kk = 0; kk < 4; ++kk)
                    a[mf][kk] = *reinterpret_cast<const i32x4*>(
                        x_frag4 + (size_t)(p * 16 + wid * 4 + mf) * 4096 +
                        kk * 1024 + lane * 16);

            f32x4 acc[4][4];
            #pragma unroll
            for (int i = 0; i < 4; ++i)
                #pragma unroll
                for (int k = 0; k < 4; ++k) acc[i][k] = (f32x4)(0.0f);

            #pragma unroll
            for (int kk = 0; kk < 4; ++kk) {
                i32x8 b8[4];
                #pragma unroll
                for (int nf = 0; nf < 4; ++nf)
                    b8[nf] = pad8(*reinterpret_cast<const i32x4*>(
                        bb + kk * 4096 + nf * 1024));
                #pragma unroll
                for (int mf = 0; mf < 4; ++mf)
                    #pragma unroll
                    for (int nf = 0; nf < 4; ++nf)
                        acc[mf][nf] = __builtin_amdgcn_mfma_scale_f32_16x16x128_f8f6f4(
                            pad8(a[mf][kk]), b8[nf], acc[mf][nf],
                            4, 4, 0, SC1, 0, SC1);
            }

            const int rbase = p * 256 + wid * 64 + g * 4;
            #pragma unroll
            for (int mf = 0; mf < 4; ++mf) {
                const float4 nv = *reinterpret_cast<const float4*>(
                    neg + rbase + mf * 16);
                #pragma unroll
                for (int jj = 0; jj < 4; ++jj) {
                    const float thr = (&nv.x)[jj] - MARGIN;
                    #pragma unroll
                    for (int nf = 0; nf < 4; ++nf)
                        sum += fmaxf(acc[mf][nf][jj] * INV_SCALE - thr, 0.0f);
                }
            }
        }
        __syncthreads();          // LDS reads done before next stage overwrites
    }

    // ---- block reduction ----
    #pragma unroll
    for (int off = 32; off; off >>= 1) sum += __shfl_down(sum, off);
    __shared__ float red[4];
    if (lane == 0) red[wid] = sum;
    __syncthreads();
    if (t == 0)
        partials[blockIdx.x] = red[0] + red[1] + red[2] + red[3];
}

// Kernel 3: deterministic final reduction of 500 block partials, mean over B.
__global__ __launch_bounds__(256) void reduce_kernel(
    const float* __restrict__ partials, float* __restrict__ out)
{
    float s = 0.f;
    for (int i = threadIdx.x; i < 500; i += 256) s += partials[i];
    #pragma unroll
    for (int off = 32; off; off >>= 1) s += __shfl_down(s, off);
    __shared__ float red[4];
    const int wid = threadIdx.x >> 6, lane = threadIdx.x & 63;
    if (lane == 0) red[wid] = s;
    __syncthreads();
    if (threadIdx.x == 0)
        out[0] = (red[0] + red[1] + red[2] + red[3]) * (1.0f / 1024.0f);
}

extern "C" void kernel_launch(void* const* d_in, const int* in_sizes, int n_in,
                              void* d_out, int out_size, void* d_ws, size_t ws_size,
                              hipStream_t stream)
{
    const float* inputs = (const float*)d_in[0];
    const float* emb    = (const float*)d_in[1];
    const int*   target = (const int*)d_in[2];
    float* out = (float*)d_out;
    char*  ws  = (char*)d_ws;

    unsigned char* x_frag4 = (unsigned char*)ws;                    // 256 KB
    float*         neg     = (float*)(ws + 262144);                 // 4 KB
    float*         parts   = (float*)(ws + 266240);                 // 2 KB

    prep_kernel<<<1024, 256, 0, stream>>>(inputs, emb, target, x_frag4, neg);
    gemm_fused_kernel<<<500, 256, 0, stream>>>(x_frag4, emb, neg, parts);
    reduce_kernel<<<1, 256, 0, stream>>>(parts, out);
}

// Round 15
// 97.383 us; speedup vs baseline: 1.1033x; 1.1033x over previous
//
#include <hip/hip_runtime.h>

typedef __attribute__((ext_vector_type(4))) float f32x4;
typedef __attribute__((ext_vector_type(4))) int   i32x4;
typedef __attribute__((ext_vector_type(8))) int   i32x8;

#define MARGIN 0.1f
#define SC1 0x7F7F7F7F            // E8M0 unit scale (2^0) for all 32-blocks
#define INV_SCALE (1.0f/2048.0f)  // undo x*32 and e*64 pre-scaling

// fp4 e2m1 quantizer (verified R10): grid {0,.5,1,1.5,2,3,4,6}, sign bit3
__device__ __forceinline__ unsigned int nib4(float a) {
    const float m = fabsf(a);
    unsigned int c = (unsigned)(m > 0.25f) + (m > 0.75f) + (m > 1.25f) +
                     (m > 1.75f) + (m > 2.5f) + (m > 3.5f) + (m > 5.0f);
    return c | ((__builtin_bit_cast(unsigned int, a) >> 28) & 8u);
}
__device__ __forceinline__ unsigned int pack8(const float4 f0, const float4 f1,
                                              float s) {
    return  nib4(f0.x * s)         | (nib4(f0.y * s) << 4)  |
           (nib4(f0.z * s) << 8)   | (nib4(f0.w * s) << 12) |
           (nib4(f1.x * s) << 16)  | (nib4(f1.y * s) << 20) |
           (nib4(f1.z * s) << 24)  | (nib4(f1.w * s) << 28);
}
__device__ __forceinline__ i32x8 pad8(const i32x4 v) {
    return (i32x8){v[0], v[1], v[2], v[3], 0, 0, 0, 0};
}

__device__ __forceinline__ void gload_lds16(const void* g, void* l) {
    __builtin_amdgcn_global_load_lds(
        (const __attribute__((address_space(1))) unsigned int*)g,
        (__attribute__((address_space(3))) unsigned int*)l, 16, 0, 0);
}

// Kernel 1 (fused, R10-verified): blocks 0..1999 convert emb f32 -> fp4(e*64)
// frag-major tiles (tile*16384 + kk*4096 + nf*1024 + lane*16). Blocks
// 2000..3023: L2-normalize inputs -> fp4(x*32) A-frags; neg[b] = exact f32 dot.
__global__ __launch_bounds__(256) void prep_convert_kernel(
    const float* __restrict__ inputs, const float* __restrict__ emb,
    const int* __restrict__ target, unsigned char* __restrict__ x_frag4,
    float* __restrict__ neg, unsigned char* __restrict__ emb4)
{
    const int t = threadIdx.x;
    __shared__ float s_ss[4], s_de[4];
    if (blockIdx.x < 2000) {
        const int nt = blockIdx.x;
        const int lane6 = t & 63, nf = t >> 6;
        const int lrow = lane6 & 15, g = lane6 >> 4;
        const float* src = emb + (size_t)(nt * 64 + nf * 16 + lrow) * 512 + g * 32;
        unsigned char* dst = emb4 + (size_t)nt * 16384 + nf * 1024 + lane6 * 16;
        #pragma unroll
        for (int kk = 0; kk < 4; ++kk) {
            const float4* s4 = reinterpret_cast<const float4*>(src + kk * 128);
            unsigned int w[4];
            #pragma unroll
            for (int d = 0; d < 4; ++d)
                w[d] = pack8(s4[2 * d], s4[2 * d + 1], 64.0f);
            *reinterpret_cast<uint4*>(dst + kk * 4096) =
                make_uint4(w[0], w[1], w[2], w[3]);
        }
    } else {
        const int b = blockIdx.x - 2000;
        const float2 v = *reinterpret_cast<const float2*>(inputs + (size_t)b * 512 + t * 2);
        const int tgt = target[b];
        const float2 e = *reinterpret_cast<const float2*>(emb + (size_t)tgt * 512 + t * 2);
        float ss = v.x * v.x + v.y * v.y;
        float de = v.x * e.x + v.y * e.y;
        #pragma unroll
        for (int off = 32; off; off >>= 1) {
            ss += __shfl_down(ss, off);
            de += __shfl_down(de, off);
        }
        const int wid = t >> 6, lane = t & 63;
        if (lane == 0) { s_ss[wid] = ss; s_de[wid] = de; }
        __syncthreads();
        const float tss = s_ss[0] + s_ss[1] + s_ss[2] + s_ss[3];
        const float tde = s_de[0] + s_de[1] + s_de[2] + s_de[3];
        const float inv = 1.0f / fmaxf(sqrtf(tss), 1e-12f);
        const float sc = inv * 32.0f;
        const int addr = (b >> 4) * 4096 + (t >> 6) * 1024 +
                         ((((t >> 4) & 3) * 16 + (b & 15)) * 16) + (t & 15);
        x_frag4[addr] = (unsigned char)(nib4(v.x * sc) | (nib4(v.y * sc) << 4));
        if (t == 0) neg[b] = tde * inv;
    }
}

// Kernel 2: 8-phase-style schedule (T3+T4+T5). 500 blocks x 256 thr.
// Block = (m-quarter mq, n-group grp): 256 m-rows x 16 contiguous emb4 tiles.
// Triple-buffered LDS (3 x 16 KB), 2-tiles-ahead prefetch via global_load_lds,
// counted vmcnt(4) at tile boundaries (loads >=2 tiles old when waited).
// Per tile: 4 phases {4 ds_read_b128 | 1 stage-load for j+2 | barrier |
// lgkmcnt(0) | setprio + 16 MFMA + setprio | barrier}. areg prepadded i32x8.
__global__ __launch_bounds__(256) void gemm_tiled_kernel(
    const unsigned char* __restrict__ x_frag4, const unsigned char* __restrict__ emb4,
    const float* __restrict__ neg, float* __restrict__ partials)
{
    __shared__ unsigned char btile[49152];        // 3 x 16 KB rotating buffers
    const int t = threadIdx.x;
    const int wid = t >> 6, lane = t & 63;
    const int g = lane >> 4;
    const int bx = blockIdx.x;
    const int mq = bx & 3;                        // m-quarter 0..3
    const int grp = bx >> 2;                      // n-group 0..124
    const int t0 = grp * 16;                      // first of 16 contiguous tiles

    // ---- areg: 16 frags (rows mq*256..+255), zero-padded i32x8, persistent ----
    i32x8 a8[4][4];                               // 128 VGPR
    #pragma unroll
    for (int mf = 0; mf < 4; ++mf)
        #pragma unroll
        for (int kk = 0; kk < 4; ++kk)
            a8[mf][kk] = pad8(*reinterpret_cast<const i32x4*>(
                x_frag4 + (size_t)(mq * 16 + wid * 4 + mf) * 4096 +
                kk * 1024 + lane * 16));

    // ---- neg values for this thread's 16 output rows (loop-invariant) ----
    const int rbase = mq * 256 + wid * 64 + g * 4;
    float4 nv[4];
    #pragma unroll
    for (int mf = 0; mf < 4; ++mf)
        nv[mf] = *reinterpret_cast<const float4*>(neg + rbase + mf * 16);

#define STAGEFULL(lb, tile)                                                   \
    {                                                                         \
        const size_t gb = (size_t)(tile) * 16384 + t * 16;                    \
        _Pragma("unroll")                                                     \
        for (int p = 0; p < 4; ++p)                                           \
            gload_lds16(emb4 + gb + p * 4096,                                 \
                        btile + (lb) + p * 4096 + t * 16);                    \
    }

    // prologue: stage tiles t0 -> buf0, t0+1 -> buf1 (8 loads outstanding)
    unsigned lb0 = 0, lb1 = 16384, lb2 = 32768;
    STAGEFULL(lb0, t0);
    STAGEFULL(lb1, t0 + 1);

    float sum = 0.0f;

    #pragma unroll 1
    for (int j = 0; j < 16; ++j) {
        // tile-boundary wait: tile j's 4 loads are the oldest; keep j+1's in flight
        if (j < 15) asm volatile("s_waitcnt vmcnt(4)" ::: "memory");
        else        asm volatile("s_waitcnt vmcnt(0)" ::: "memory");
        __builtin_amdgcn_s_barrier();

        f32x4 acc[4][4];
        #pragma unroll
        for (int i = 0; i < 4; ++i)
            #pragma unroll
            for (int k = 0; k < 4; ++k) acc[i][k] = (f32x4)(0.0f);

        const bool pf = (j + 2 < 16);
        const size_t gb2 = (size_t)(t0 + j + 2) * 16384 + t * 16;

        #pragma unroll
        for (int kk = 0; kk < 4; ++kk) {
            // phase kk: ds_read quarter kk | 1 prefetch load | barrier | MFMA
            i32x8 b8[4];
            #pragma unroll
            for (int nf = 0; nf < 4; ++nf)
                b8[nf] = pad8(*reinterpret_cast<const i32x4*>(
                    btile + lb0 + kk * 4096 + nf * 1024 + lane * 16));
            if (pf)
                gload_lds16(emb4 + gb2 + kk * 4096,
                            btile + lb2 + kk * 4096 + t * 16);
            __builtin_amdgcn_s_barrier();
            asm volatile("s_waitcnt lgkmcnt(0)" ::: "memory");
            __builtin_amdgcn_sched_barrier(0);
            __builtin_amdgcn_s_setprio(1);
            #pragma unroll
            for (int mf = 0; mf < 4; ++mf)
                #pragma unroll
                for (int nf = 0; nf < 4; ++nf)
                    acc[mf][nf] = __builtin_amdgcn_mfma_scale_f32_16x16x128_f8f6f4(
                        a8[mf][kk], b8[nf], acc[mf][nf], 4, 4, 0, SC1, 0, SC1);
            __builtin_amdgcn_s_setprio(0);
            __builtin_amdgcn_sched_barrier(0);
            __builtin_amdgcn_s_barrier();
        }

        // ---- fused epilogue: relu(margin + dot - neg[m]) summed ----
        #pragma unroll
        for (int mf = 0; mf < 4; ++mf)
            #pragma unroll
            for (int jj = 0; jj < 4; ++jj) {
                const float thr = (&nv[mf].x)[jj] - MARGIN;
                #pragma unroll
                for (int nf = 0; nf < 4; ++nf)
                    sum += fmaxf(acc[mf][nf][jj] * INV_SCALE - thr, 0.0f);
            }

        // rotate buffers: read buf <- lb1, spare <- lb0
        const unsigned tmp = lb0; lb0 = lb1; lb1 = lb2; lb2 = tmp;
    }

    // ---- block reduction ----
    __syncthreads();
    #pragma unroll
    for (int off = 32; off; off >>= 1) sum += __shfl_down(sum, off);
    float* red = reinterpret_cast<float*>(btile);
    if (lane == 0) red[wid] = sum;
    __syncthreads();
    if (t == 0)
        partials[bx] = red[0] + red[1] + red[2] + red[3];
}

// Kernel 3: deterministic final reduction of 500 block partials, mean over B.
__global__ __launch_bounds__(256) void reduce_kernel(
    const float* __restrict__ partials, float* __restrict__ out)
{
    float s = 0.f;
    for (int i = threadIdx.x; i < 500; i += 256) s += partials[i];
    #pragma unroll
    for (int off = 32; off; off >>= 1) s += __shfl_down(s, off);
    __shared__ float red[4];
    const int wid = threadIdx.x >> 6, lane = threadIdx.x & 63;
    if (lane == 0) red[wid] = s;
    __syncthreads();
    if (threadIdx.x == 0)
        out[0] = (red[0] + red[1] + red[2] + red[3]) * (1.0f / 1024.0f);
}

extern "C" void kernel_launch(void* const* d_in, const int* in_sizes, int n_in,
                              void* d_out, int out_size, void* d_ws, size_t ws_size,
                              hipStream_t stream)
{
    const float* inputs = (const float*)d_in[0];
    const float* emb    = (const float*)d_in[1];
    const int*   target = (const int*)d_in[2];
    float* out = (float*)d_out;
    char*  ws  = (char*)d_ws;

    unsigned char* x_frag4 = (unsigned char*)ws;                    // 256 KB
    float*         neg     = (float*)(ws + 262144);                 // 4 KB
    float*         parts   = (float*)(ws + 266240);                 // 2 KB
    unsigned char* emb4    = (unsigned char*)(ws + 1048576);        // 32.8 MB

    prep_convert_kernel<<<3024, 256, 0, stream>>>(inputs, emb, target,
                                                  x_frag4, neg, emb4);
    gemm_tiled_kernel<<<500, 256, 0, stream>>>(x_frag4, emb4, neg, parts);
    reduce_kernel<<<1, 256, 0, stream>>>(parts, out);
}

// Round 16
// 95.817 us; speedup vs baseline: 1.1214x; 1.0163x over previous
//
#include <hip/hip_runtime.h>

typedef __attribute__((ext_vector_type(4))) float f32x4;
typedef __attribute__((ext_vector_type(4))) int   i32x4;
typedef __attribute__((ext_vector_type(8))) int   i32x8;

#define MARGIN 0.1f
#define SC1 0x7F7F7F7F            // E8M0 unit scale (2^0) for all 32-blocks
#define INV_SCALE (1.0f/2048.0f)  // undo x*32 and e*64 pre-scaling

// fp4 e2m1 quantizer (verified R10): grid {0,.5,1,1.5,2,3,4,6}, sign bit3
__device__ __forceinline__ unsigned int nib4(float a) {
    const float m = fabsf(a);
    unsigned int c = (unsigned)(m > 0.25f) + (m > 0.75f) + (m > 1.25f) +
                     (m > 1.75f) + (m > 2.5f) + (m > 3.5f) + (m > 5.0f);
    return c | ((__builtin_bit_cast(unsigned int, a) >> 28) & 8u);
}
__device__ __forceinline__ unsigned int pack8(const float4 f0, const float4 f1,
                                              float s) {
    return  nib4(f0.x * s)         | (nib4(f0.y * s) << 4)  |
           (nib4(f0.z * s) << 8)   | (nib4(f0.w * s) << 12) |
           (nib4(f1.x * s) << 16)  | (nib4(f1.y * s) << 20) |
           (nib4(f1.z * s) << 24)  | (nib4(f1.w * s) << 28);
}
__device__ __forceinline__ i32x8 pad8(const i32x4 v) {
    return (i32x8){v[0], v[1], v[2], v[3], 0, 0, 0, 0};
}

__device__ __forceinline__ void gload_lds16(const void* g, void* l) {
    __builtin_amdgcn_global_load_lds(
        (const __attribute__((address_space(1))) unsigned int*)g,
        (__attribute__((address_space(3))) unsigned int*)l, 16, 0, 0);
}

// Kernel 1 (fused, R10-verified): blocks 0..1999 convert emb f32 -> fp4(e*64)
// frag-major tiles (tile*16384 + kk*4096 + nf*1024 + lane*16). Blocks
// 2000..3023: L2-normalize inputs -> fp4(x*32) A-frags; neg[b] = exact f32 dot.
__global__ __launch_bounds__(256) void prep_convert_kernel(
    const float* __restrict__ inputs, const float* __restrict__ emb,
    const int* __restrict__ target, unsigned char* __restrict__ x_frag4,
    float* __restrict__ neg, unsigned char* __restrict__ emb4)
{
    const int t = threadIdx.x;
    __shared__ float s_ss[4], s_de[4];
    if (blockIdx.x < 2000) {
        const int nt = blockIdx.x;
        const int lane6 = t & 63, nf = t >> 6;
        const int lrow = lane6 & 15, g = lane6 >> 4;
        const float* src = emb + (size_t)(nt * 64 + nf * 16 + lrow) * 512 + g * 32;
        unsigned char* dst = emb4 + (size_t)nt * 16384 + nf * 1024 + lane6 * 16;
        #pragma unroll
        for (int kk = 0; kk < 4; ++kk) {
            const float4* s4 = reinterpret_cast<const float4*>(src + kk * 128);
            unsigned int w[4];
            #pragma unroll
            for (int d = 0; d < 4; ++d)
                w[d] = pack8(s4[2 * d], s4[2 * d + 1], 64.0f);
            *reinterpret_cast<uint4*>(dst + kk * 4096) =
                make_uint4(w[0], w[1], w[2], w[3]);
        }
    } else {
        const int b = blockIdx.x - 2000;
        const float2 v = *reinterpret_cast<const float2*>(inputs + (size_t)b * 512 + t * 2);
        const int tgt = target[b];
        const float2 e = *reinterpret_cast<const float2*>(emb + (size_t)tgt * 512 + t * 2);
        float ss = v.x * v.x + v.y * v.y;
        float de = v.x * e.x + v.y * e.y;
        #pragma unroll
        for (int off = 32; off; off >>= 1) {
            ss += __shfl_down(ss, off);
            de += __shfl_down(de, off);
        }
        const int wid = t >> 6, lane = t & 63;
        if (lane == 0) { s_ss[wid] = ss; s_de[wid] = de; }
        __syncthreads();
        const float tss = s_ss[0] + s_ss[1] + s_ss[2] + s_ss[3];
        const float tde = s_de[0] + s_de[1] + s_de[2] + s_de[3];
        const float inv = 1.0f / fmaxf(sqrtf(tss), 1e-12f);
        const float sc = inv * 32.0f;
        const int addr = (b >> 4) * 4096 + (t >> 6) * 1024 +
                         ((((t >> 4) & 3) * 16 + (b & 15)) * 16) + (t & 15);
        x_frag4[addr] = (unsigned char)(nib4(v.x * sc) | (nib4(v.y * sc) << 4));
        if (t == 0) neg[b] = tde * inv;
    }
}

// Kernel 2: occupancy-first. 500 blocks x 512 thr (8 waves x 32 m-rows each).
// Per-wave state <=128 VGPR: areg UNPADDED i32x4 (32), acc 32, nv 8, b8 32
// -> 2 blocks/CU = 16 waves/CU for real latency hiding. R13 loop skeleton:
// double-buffered LDS, global_load_lds, counted vmcnt(2), 2 barriers/tile.
__global__ __launch_bounds__(512) void gemm_tiled_kernel(
    const unsigned char* __restrict__ x_frag4, const unsigned char* __restrict__ emb4,
    const float* __restrict__ neg, float* __restrict__ partials)
{
    __shared__ unsigned char btile[32768];        // 2 x 16 KB double buffer
    const int t = threadIdx.x;                    // 0..511
    const int wid = t >> 6, lane = t & 63;
    const int g = lane >> 4;
    const int bx = blockIdx.x;
    const int mq = bx & 3;                        // m-quarter 0..3
    const int grp = bx >> 2;                      // n-group 0..124
    const int t0 = grp * 16;                      // first of 16 contiguous tiles

    // ---- areg: 2 frags (rows mq*256 + wid*32 .. +31), UNPADDED, 32 VGPR ----
    i32x4 a4[2][4];
    #pragma unroll
    for (int mf = 0; mf < 2; ++mf)
        #pragma unroll
        for (int kk = 0; kk < 4; ++kk)
            a4[mf][kk] = *reinterpret_cast<const i32x4*>(
                x_frag4 + (size_t)(mq * 16 + wid * 2 + mf) * 4096 +
                kk * 1024 + lane * 16);

    // ---- neg values for this thread's 8 output rows (loop-invariant) ----
    const int rbase = mq * 256 + wid * 32 + g * 4;
    float4 nv[2];
    #pragma unroll
    for (int mf = 0; mf < 2; ++mf)
        nv[mf] = *reinterpret_cast<const float4*>(neg + rbase + mf * 16);

#define STAGE(buf, tile)                                                      \
    {                                                                         \
        const size_t gb = (size_t)(tile) * 16384 + t * 16;                    \
        gload_lds16(emb4 + gb, &btile[(buf) * 16384 + t * 16]);               \
        gload_lds16(emb4 + gb + 8192,                                         \
                    &btile[(buf) * 16384 + t * 16 + 8192]);                   \
    }

    STAGE(0, t0);
    float sum = 0.0f;

    #pragma unroll 1
    for (int j = 0; j < 16; ++j) {
        if (j + 1 < 16) {
            STAGE((j + 1) & 1, t0 + j + 1);
            asm volatile("s_waitcnt vmcnt(2)" ::: "memory");
        } else {
            asm volatile("s_waitcnt vmcnt(0)" ::: "memory");
        }
        __builtin_amdgcn_s_barrier();             // tile j staged for all
        __builtin_amdgcn_sched_barrier(0);

        f32x4 acc[2][4];
        #pragma unroll
        for (int i = 0; i < 2; ++i)
            #pragma unroll
            for (int k = 0; k < 4; ++k) acc[i][k] = (f32x4)(0.0f);

        const unsigned char* bb = btile + (j & 1) * 16384 + lane * 16;
        #pragma unroll
        for (int kk = 0; kk < 4; ++kk) {
            i32x8 b8[4];
            #pragma unroll
            for (int nf = 0; nf < 4; ++nf)
                b8[nf] = pad8(*reinterpret_cast<const i32x4*>(
                    bb + kk * 4096 + nf * 1024));
            #pragma unroll
            for (int mf = 0; mf < 2; ++mf) {
                const i32x8 a8 = pad8(a4[mf][kk]);
                #pragma unroll
                for (int nf = 0; nf < 4; ++nf)
                    acc[mf][nf] = __builtin_amdgcn_mfma_scale_f32_16x16x128_f8f6f4(
                        a8, b8[nf], acc[mf][nf], 4, 4, 0, SC1, 0, SC1);
            }
        }

        // ---- fused epilogue: relu(margin + dot - neg[m]) summed ----
        #pragma unroll
        for (int mf = 0; mf < 2; ++mf)
            #pragma unroll
            for (int jj = 0; jj < 4; ++jj) {
                const float thr = (&nv[mf].x)[jj] - MARGIN;
                #pragma unroll
                for (int nf = 0; nf < 4; ++nf)
                    sum += fmaxf(acc[mf][nf][jj] * INV_SCALE - thr, 0.0f);
            }
        __builtin_amdgcn_sched_barrier(0);
        __builtin_amdgcn_s_barrier();             // all done reading buf[j&1]
    }

    // ---- block reduction ----
    __syncthreads();
    #pragma unroll
    for (int off = 32; off; off >>= 1) sum += __shfl_down(sum, off);
    float* red = reinterpret_cast<float*>(btile);
    if (lane == 0) red[wid] = sum;
    __syncthreads();
    if (t == 0) {
        float tot = 0.f;
        #pragma unroll
        for (int w = 0; w < 8; ++w) tot += red[w];
        partials[bx] = tot;
    }
}

// Kernel 3: deterministic final reduction of 500 block partials, mean over B.
__global__ __launch_bounds__(256) void reduce_kernel(
    const float* __restrict__ partials, float* __restrict__ out)
{
    float s = 0.f;
    for (int i = threadIdx.x; i < 500; i += 256) s += partials[i];
    #pragma unroll
    for (int off = 32; off; off >>= 1) s += __shfl_down(s, off);
    __shared__ float red[4];
    const int wid = threadIdx.x >> 6, lane = threadIdx.x & 63;
    if (lane == 0) red[wid] = s;
    __syncthreads();
    if (threadIdx.x == 0)
        out[0] = (red[0] + red[1] + red[2] + red[3]) * (1.0f / 1024.0f);
}

extern "C" void kernel_launch(void* const* d_in, const int* in_sizes, int n_in,
                              void* d_out, int out_size, void* d_ws, size_t ws_size,
                              hipStream_t stream)
{
    const float* inputs = (const float*)d_in[0];
    const float* emb    = (const float*)d_in[1];
    const int*   target = (const int*)d_in[2];
    float* out = (float*)d_out;
    char*  ws  = (char*)d_ws;

    unsigned char* x_frag4 = (unsigned char*)ws;                    // 256 KB
    float*         neg     = (float*)(ws + 262144);                 // 4 KB
    float*         parts   = (float*)(ws + 266240);                 // 2 KB
    unsigned char* emb4    = (unsigned char*)(ws + 1048576);        // 32.8 MB

    prep_convert_kernel<<<3024, 256, 0, stream>>>(inputs, emb, target,
                                                  x_frag4, neg, emb4);
    gemm_tiled_kernel<<<500, 512, 0, stream>>>(x_frag4, emb4, neg, parts);
    reduce_kernel<<<1, 256, 0, stream>>>(parts, out);
}

// Round 17
// 94.658 us; speedup vs baseline: 1.1351x; 1.0122x over previous
//
#include <hip/hip_runtime.h>

typedef __attribute__((ext_vector_type(4))) float f32x4;
typedef __attribute__((ext_vector_type(4))) int   i32x4;
typedef __attribute__((ext_vector_type(8))) int   i32x8;

#define MARGIN 0.1f
#define SC1 0x7F7F7F7F            // E8M0 unit scale (2^0) for all 32-blocks
#define INV_SCALE (1.0f/2048.0f)  // undo x*32 and e*64 pre-scaling

// fp4 e2m1 quantizer (verified R10): grid {0,.5,1,1.5,2,3,4,6}, sign bit3
__device__ __forceinline__ unsigned int nib4(float a) {
    const float m = fabsf(a);
    unsigned int c = (unsigned)(m > 0.25f) + (m > 0.75f) + (m > 1.25f) +
                     (m > 1.75f) + (m > 2.5f) + (m > 3.5f) + (m > 5.0f);
    return c | ((__builtin_bit_cast(unsigned int, a) >> 28) & 8u);
}
__device__ __forceinline__ unsigned int pack8(const float4 f0, const float4 f1,
                                              float s) {
    return  nib4(f0.x * s)         | (nib4(f0.y * s) << 4)  |
           (nib4(f0.z * s) << 8)   | (nib4(f0.w * s) << 12) |
           (nib4(f1.x * s) << 16)  | (nib4(f1.y * s) << 20) |
           (nib4(f1.z * s) << 24)  | (nib4(f1.w * s) << 28);
}
__device__ __forceinline__ i32x8 pad8(const i32x4 v) {
    return (i32x8){v[0], v[1], v[2], v[3], 0, 0, 0, 0};
}

__device__ __forceinline__ void gload_lds16(const void* g, void* l) {
    __builtin_amdgcn_global_load_lds(
        (const __attribute__((address_space(1))) unsigned int*)g,
        (__attribute__((address_space(3))) unsigned int*)l, 16, 0, 0);
}

// Kernel 1 (fused, R10-verified): blocks 0..1999 convert emb f32 -> fp4(e*64)
// frag-major tiles (tile*16384 + kk*4096 + nf*1024 + lane*16). Blocks
// 2000..3023: L2-normalize inputs -> fp4(x*32) A-frags; neg[b] = exact f32 dot.
__global__ __launch_bounds__(256) void prep_convert_kernel(
    const float* __restrict__ inputs, const float* __restrict__ emb,
    const int* __restrict__ target, unsigned char* __restrict__ x_frag4,
    float* __restrict__ neg, unsigned char* __restrict__ emb4)
{
    const int t = threadIdx.x;
    __shared__ float s_ss[4], s_de[4];
    if (blockIdx.x < 2000) {
        const int nt = blockIdx.x;
        const int lane6 = t & 63, nf = t >> 6;
        const int lrow = lane6 & 15, g = lane6 >> 4;
        const float* src = emb + (size_t)(nt * 64 + nf * 16 + lrow) * 512 + g * 32;
        unsigned char* dst = emb4 + (size_t)nt * 16384 + nf * 1024 + lane6 * 16;
        #pragma unroll
        for (int kk = 0; kk < 4; ++kk) {
            const float4* s4 = reinterpret_cast<const float4*>(src + kk * 128);
            unsigned int w[4];
            #pragma unroll
            for (int d = 0; d < 4; ++d)
                w[d] = pack8(s4[2 * d], s4[2 * d + 1], 64.0f);
            *reinterpret_cast<uint4*>(dst + kk * 4096) =
                make_uint4(w[0], w[1], w[2], w[3]);
        }
    } else {
        const int b = blockIdx.x - 2000;
        const float2 v = *reinterpret_cast<const float2*>(inputs + (size_t)b * 512 + t * 2);
        const int tgt = target[b];
        const float2 e = *reinterpret_cast<const float2*>(emb + (size_t)tgt * 512 + t * 2);
        float ss = v.x * v.x + v.y * v.y;
        float de = v.x * e.x + v.y * e.y;
        #pragma unroll
        for (int off = 32; off; off >>= 1) {
            ss += __shfl_down(ss, off);
            de += __shfl_down(de, off);
        }
        const int wid = t >> 6, lane = t & 63;
        if (lane == 0) { s_ss[wid] = ss; s_de[wid] = de; }
        __syncthreads();
        const float tss = s_ss[0] + s_ss[1] + s_ss[2] + s_ss[3];
        const float tde = s_de[0] + s_de[1] + s_de[2] + s_de[3];
        const float inv = 1.0f / fmaxf(sqrtf(tss), 1e-12f);
        const float sc = inv * 32.0f;
        const int addr = (b >> 4) * 4096 + (t >> 6) * 1024 +
                         ((((t >> 4) & 3) * 16 + (b & 15)) * 16) + (t & 15);
        x_frag4[addr] = (unsigned char)(nib4(v.x * sc) | (nib4(v.y * sc) << 4));
        if (t == 0) neg[b] = tde * inv;
    }
}

// Kernel 2: mf=4 AND 8 waves/CU. 250 blocks x 512 thr; block = (mhalf,
// 16-tile group); wave owns 64 m-rows: areg UNPADDED i32x4[4][4] (64 VGPR,
// padded at use). Per-CU tile-step: MFMA 2854 cyc > LDS 1506 cyc (B-read
// traffic halved vs R16) -> MFMA-pipe-bound. Double-buffered LDS,
// global_load_lds, counted vmcnt(2), 2 barriers/tile (R13 skeleton).
__global__ __launch_bounds__(512) void gemm_tiled_kernel(
    const unsigned char* __restrict__ x_frag4, const unsigned char* __restrict__ emb4,
    const float* __restrict__ neg, float* __restrict__ partials)
{
    __shared__ unsigned char btile[32768];        // 2 x 16 KB double buffer
    const int t = threadIdx.x;                    // 0..511
    const int wid = t >> 6, lane = t & 63;
    const int g = lane >> 4;
    const int bx = blockIdx.x;
    const int mhalf = bx & 1;                     // m-half 0..1
    const int grp = bx >> 1;                      // n-group 0..124
    const int t0 = grp * 16;                      // first of 16 contiguous tiles

    // ---- areg: 4 frags (rows mhalf*512 + wid*64 .. +63), UNPADDED, 64 VGPR ----
    i32x4 a4[4][4];
    #pragma unroll
    for (int mf = 0; mf < 4; ++mf)
        #pragma unroll
        for (int kk = 0; kk < 4; ++kk)
            a4[mf][kk] = *reinterpret_cast<const i32x4*>(
                x_frag4 + (size_t)(mhalf * 32 + wid * 4 + mf) * 4096 +
                kk * 1024 + lane * 16);

    // ---- neg values for this thread's 16 output rows (loop-invariant) ----
    const int rbase = mhalf * 512 + wid * 64 + g * 4;
    float4 nv[4];
    #pragma unroll
    for (int mf = 0; mf < 4; ++mf)
        nv[mf] = *reinterpret_cast<const float4*>(neg + rbase + mf * 16);

#define STAGE(buf, tile)                                                      \
    {                                                                         \
        const size_t gb = (size_t)(tile) * 16384 + t * 16;                    \
        gload_lds16(emb4 + gb, &btile[(buf) * 16384 + t * 16]);               \
        gload_lds16(emb4 + gb + 8192,                                         \
                    &btile[(buf) * 16384 + t * 16 + 8192]);                   \
    }

    STAGE(0, t0);
    float sum = 0.0f;

    #pragma unroll 1
    for (int j = 0; j < 16; ++j) {
        if (j + 1 < 16) {
            STAGE((j + 1) & 1, t0 + j + 1);
            asm volatile("s_waitcnt vmcnt(2)" ::: "memory");
        } else {
            asm volatile("s_waitcnt vmcnt(0)" ::: "memory");
        }
        __builtin_amdgcn_s_barrier();             // tile j staged for all
        __builtin_amdgcn_sched_barrier(0);

        f32x4 acc[4][4];
        #pragma unroll
        for (int i = 0; i < 4; ++i)
            #pragma unroll
            for (int k = 0; k < 4; ++k) acc[i][k] = (f32x4)(0.0f);

        const unsigned char* bb = btile + (j & 1) * 16384 + lane * 16;
        #pragma unroll
        for (int kk = 0; kk < 4; ++kk) {
            i32x8 b8[4];
            #pragma unroll
            for (int nf = 0; nf < 4; ++nf)
                b8[nf] = pad8(*reinterpret_cast<const i32x4*>(
                    bb + kk * 4096 + nf * 1024));
            #pragma unroll
            for (int mf = 0; mf < 4; ++mf) {
                const i32x8 a8 = pad8(a4[mf][kk]);
                #pragma unroll
                for (int nf = 0; nf < 4; ++nf)
                    acc[mf][nf] = __builtin_amdgcn_mfma_scale_f32_16x16x128_f8f6f4(
                        a8, b8[nf], acc[mf][nf], 4, 4, 0, SC1, 0, SC1);
            }
        }

        // ---- fused epilogue: relu(margin + dot - neg[m]) summed ----
        #pragma unroll
        for (int mf = 0; mf < 4; ++mf)
            #pragma unroll
            for (int jj = 0; jj < 4; ++jj) {
                const float thr = (&nv[mf].x)[jj] - MARGIN;
                #pragma unroll
                for (int nf = 0; nf < 4; ++nf)
                    sum += fmaxf(acc[mf][nf][jj] * INV_SCALE - thr, 0.0f);
            }
        __builtin_amdgcn_sched_barrier(0);
        __builtin_amdgcn_s_barrier();             // all done reading buf[j&1]
    }

    // ---- block reduction ----
    __syncthreads();
    #pragma unroll
    for (int off = 32; off; off >>= 1) sum += __shfl_down(sum, off);
    float* red = reinterpret_cast<float*>(btile);
    if (lane == 0) red[wid] = sum;
    __syncthreads();
    if (t == 0) {
        float tot = 0.f;
        #pragma unroll
        for (int w = 0; w < 8; ++w) tot += red[w];
        partials[bx] = tot;
    }
}

// Kernel 3: deterministic final reduction of 250 block partials, mean over B.
__global__ __launch_bounds__(256) void reduce_kernel(
    const float* __restrict__ partials, float* __restrict__ out)
{
    float s = (threadIdx.x < 250) ? partials[threadIdx.x] : 0.f;
    #pragma unroll
    for (int off = 32; off; off >>= 1) s += __shfl_down(s, off);
    __shared__ float red[4];
    const int wid = threadIdx.x >> 6, lane = threadIdx.x & 63;
    if (lane == 0) red[wid] = s;
    __syncthreads();
    if (threadIdx.x == 0)
        out[0] = (red[0] + red[1] + red[2] + red[3]) * (1.0f / 1024.0f);
}

extern "C" void kernel_launch(void* const* d_in, const int* in_sizes, int n_in,
                              void* d_out, int out_size, void* d_ws, size_t ws_size,
                              hipStream_t stream)
{
    const float* inputs = (const float*)d_in[0];
    const float* emb    = (const float*)d_in[1];
    const int*   target = (const int*)d_in[2];
    float* out = (float*)d_out;
    char*  ws  = (char*)d_ws;

    unsigned char* x_frag4 = (unsigned char*)ws;                    // 256 KB
    float*         neg     = (float*)(ws + 262144);                 // 4 KB
    float*         parts   = (float*)(ws + 266240);                 // 1 KB
    unsigned char* emb4    = (unsigned char*)(ws + 1048576);        // 32.8 MB

    prep_convert_kernel<<<3024, 256, 0, stream>>>(inputs, emb, target,
                                                  x_frag4, neg, emb4);
    gemm_tiled_kernel<<<250, 512, 0, stream>>>(x_frag4, emb4, neg, parts);
    reduce_kernel<<<1, 256, 0, stream>>>(parts, out);
}